// Round 17
// baseline (122.890 us; speedup 1.0000x reference)
//
#include <hip/hip_runtime.h>

typedef unsigned short u16;
typedef unsigned int   u32;

typedef __bf16 bf16x8 __attribute__((ext_vector_type(8)));
typedef __bf16 bf16x4 __attribute__((ext_vector_type(4)));
typedef float  f32x4  __attribute__((ext_vector_type(4)));

__device__ __forceinline__ float bf2f(u16 v) {
    u32 u = ((u32)v) << 16; float f; __builtin_memcpy(&f, &u, 4); return f;
}
__device__ __forceinline__ u16 f2bf(float f) {
    __bf16 h = (__bf16)f; u16 r; __builtin_memcpy(&r, &h, 2); return r;
}

__device__ __forceinline__ void gload_lds16(const void* g, void* l) {
    __builtin_amdgcn_global_load_lds(
        (const __attribute__((address_space(1))) u32*)g,
        (__attribute__((address_space(3))) u32*)l, 16, 0, 0);
}

__device__ __forceinline__ void barrier_raw() {
    __builtin_amdgcn_s_barrier();
    asm volatile("" ::: "memory");
}

// Q-projection scale: 1/sqrt(64) * log2(e)  (base-2 softmax)
#define QSCALE 0.1803368801111204f

// ---------------------------------------------------------------------------
// Fused f32 -> bf16 conversion of all 6 tensors. Wo is scaled by ln_g during
// conversion (W' = g (.) Wo). Blocks >= 2048 compute the LN-fold vectors:
//   S1[n] = sum_c g[c]*Wo[n][c],  SB[n] = sum_c be[c]*Wo[n][c] + bo[n].
// ---------------------------------------------------------------------------
__global__ __launch_bounds__(256) void cvt_all(
    const float* __restrict__ q, const float* __restrict__ kv,
    const float* __restrict__ Wq, const float* __restrict__ Wk,
    const float* __restrict__ Wv, const float* __restrict__ Wo,
    const float* __restrict__ g, const float* __restrict__ be,
    const float* __restrict__ bo,
    u16* __restrict__ dst, float* __restrict__ S1, float* __restrict__ SB)
{
    const int bid = (int)blockIdx.x;
    if (bid < 2048) {
        const int total = 16 << 18;
        int i = bid * 256 + threadIdx.x;
        const int stride = 2048 * 256;
        for (; i < total; i += stride) {
            int seg = i >> 18;
            const float* s; int off = i & 262143;
            bool isWo = false;
            if (seg < 8)        { s = q;  off = i; }
            else if (seg < 12)  { s = kv; off = i - (8 << 18); }
            else if (seg == 12) { s = Wq; }
            else if (seg == 13) { s = Wk; }
            else if (seg == 14) { s = Wv; }
            else                { s = Wo; isWo = true; }
            float4 v = reinterpret_cast<const float4*>(s)[off];
            if (isWo) {
                float4 g4 = reinterpret_cast<const float4*>(g)[off & 255];
                v.x *= g4.x; v.y *= g4.y; v.z *= g4.z; v.w *= g4.w;
            }
            ushort4 o;
            o.x = f2bf(v.x); o.y = f2bf(v.y); o.z = f2bf(v.z); o.w = f2bf(v.w);
            reinterpret_cast<ushort4*>(dst)[i] = o;
        }
    } else {
        // S-vectors: one n per wave
        const int n = (bid - 2048) * 4 + (threadIdx.x >> 6);
        const int l = threadIdx.x & 63;
        const float4* wrow = reinterpret_cast<const float4*>(Wo + (size_t)n * 1024);
        float s1 = 0.f, sb = 0.f;
        #pragma unroll
        for (int j = 0; j < 4; j++) {
            int c4 = j * 64 + l;
            float4 wv = wrow[c4];
            float4 g4 = reinterpret_cast<const float4*>(g)[c4];
            float4 b4 = reinterpret_cast<const float4*>(be)[c4];
            s1 += wv.x * g4.x + wv.y * g4.y + wv.z * g4.z + wv.w * g4.w;
            sb += wv.x * b4.x + wv.y * b4.y + wv.z * b4.z + wv.w * b4.w;
        }
        #pragma unroll
        for (int d = 1; d < 64; d <<= 1) {
            s1 += __shfl_xor(s1, d);
            sb += __shfl_xor(sb, d);
        }
        if (l == 0) { S1[n] = s1; SB[n] = sb + bo[n]; }
    }
}

// ---------------------------------------------------------------------------
// 256x256 8-wave phased GEMM for the QKV projections (validated R7).
// ---------------------------------------------------------------------------
template<int KK, int MH, bool RB>
__device__ __forceinline__ void qkv_phase(
    const char* ldsb, int d, int ha, int hb, int rbB, int fr, int fq,
    bf16x8 (&bF)[4], f32x4 (&acc)[8][4])
{
    const int sw = ((KK * 4 + fq) ^ (fr & 7)) * 16;
    if (RB) {
        #pragma unroll
        for (int ni = 0; ni < 4; ni++)
            bF[ni] = *reinterpret_cast<const bf16x8*>(
                ldsb + 65536 + d * 32768 + hb * 16384 + (rbB + ni * 16 + fr) * 128 + sw);
    }
    bf16x8 aF[4];
    #pragma unroll
    for (int j = 0; j < 4; j++)
        aF[j] = *reinterpret_cast<const bf16x8*>(
            ldsb + d * 32768 + ha * 16384 + ((MH * 4 + j) * 16 + fr) * 128 + sw);
    __builtin_amdgcn_s_setprio(1);
    #pragma unroll
    for (int j = 0; j < 4; j++)
        #pragma unroll
        for (int ni = 0; ni < 4; ni++)
            acc[MH * 4 + j][ni] = __builtin_amdgcn_mfma_f32_16x16x32_bf16(
                aF[j], bF[ni], acc[MH * 4 + j][ni], 0, 0, 0);
    __builtin_amdgcn_s_setprio(0);
}

__global__ __launch_bounds__(512, 2) void gemm_qkv8(
    const u16* __restrict__ q8, const u16* __restrict__ kv8,
    const u16* __restrict__ Wq8, const u16* __restrict__ Wk8,
    const u16* __restrict__ Wv8,
    u16* __restrict__ Qb, u16* __restrict__ Kb, u16* __restrict__ Vb)
{
    __shared__ __align__(16) u16 lds[65536];   // 128 KiB
    char* ldsb = (char*)lds;

    const int tid = threadIdx.x;
    const int l = tid & 63, w = tid >> 6;
    const int fr = l & 15, fq = l >> 4;

    const int bid = (int)blockIdx.x;
    const int lbid = (bid & 7) * 32 + (bid >> 3);
    const u16 *A, *W; u16* C; float scale = 1.0f; int rt, ct;
    if (lbid < 128)      { A = q8;  W = Wq8; C = Qb; scale = QSCALE; rt = lbid >> 2; ct = lbid & 3; }
    else if (lbid < 192) { int t = lbid - 128; A = kv8; W = Wk8; C = Kb; rt = t >> 2; ct = t & 3; }
    else                 { int t = lbid - 192; A = kv8; W = Wv8; C = Vb; rt = t >> 2; ct = t & 3; }
    const int brow = rt * 256, bcol = ct * 256;

    const int wr = (w >> 2) * 128, wc = (w & 3) * 64;
    const int ha = w >> 2;
    const int hb = (w & 3) >> 1;
    const int rbB = wc & 64;

    const int srow = l >> 3;
    const int sslot = (l & 7) ^ srow;

    const u16* srcA[2][2];
    const u16* srcB[2][2];
    #pragma unroll
    for (int h = 0; h < 2; h++)
        #pragma unroll
        for (int i = 0; i < 2; i++) {
            int grow = h * 128 + (2 * w + i) * 8 + srow;
            srcA[h][i] = A + (size_t)(brow + grow) * 1024 + sslot * 8;
            srcB[h][i] = W + (size_t)(bcol + grow) * 1024 + sslot * 8;
        }

    auto stageA = [&](int kt, int d) {
        #pragma unroll
        for (int h = 0; h < 2; h++)
            #pragma unroll
            for (int i = 0; i < 2; i++)
                gload_lds16(srcA[h][i] + kt * 64,
                            ldsb + d * 32768 + h * 16384 + (2 * w + i) * 1024);
    };
    auto stageBh = [&](int kt, int d, int h) {
        #pragma unroll
        for (int i = 0; i < 2; i++)
            gload_lds16(srcB[h][i] + kt * 64,
                        ldsb + 65536 + d * 32768 + h * 16384 + (2 * w + i) * 1024);
    };

    f32x4 acc[8][4] = {};

    stageA(0, 0); stageBh(0, 0, 0); stageBh(0, 0, 1);
    asm volatile("s_waitcnt vmcnt(0)" ::: "memory");
    barrier_raw();

    for (int kt = 0; kt < 16; ++kt) {
        const int d = kt & 1, nd = d ^ 1;
        const bool pre = (kt < 15);
        bf16x8 bF[4];

        if (pre) stageA(kt + 1, nd);
        qkv_phase<0, 0, true >(ldsb, d, ha, hb, rbB, fr, fq, bF, acc);
        barrier_raw();
        if (pre) stageBh(kt + 1, nd, 0);
        qkv_phase<0, 1, false>(ldsb, d, ha, hb, rbB, fr, fq, bF, acc);
        barrier_raw();
        if (pre) stageBh(kt + 1, nd, 1);
        qkv_phase<1, 0, true >(ldsb, d, ha, hb, rbB, fr, fq, bF, acc);
        barrier_raw();
        qkv_phase<1, 1, false>(ldsb, d, ha, hb, rbB, fr, fq, bF, acc);
        asm volatile("s_waitcnt vmcnt(0)" ::: "memory");
        barrier_raw();
    }

    #pragma unroll
    for (int mi = 0; mi < 8; mi++) {
        int row = brow + wr + mi * 16 + fq * 4;
        #pragma unroll
        for (int ni = 0; ni < 4; ni++) {
            int col = bcol + wc + ni * 16 + fr;
            #pragma unroll
            for (int r = 0; r < 4; r++)
                C[(size_t)(row + r) * 1024 + col] = f2bf(acc[mi][ni][r] * scale);
        }
    }
}

// ---------------------------------------------------------------------------
// 128x256 8-wave phased GEMM for the output projection, with fused LN:
// out[r][n] = rs[r]*(acc[r][n] - mu[r]*S1[n]) + SB[n],  acc = A @ W'^T.
// Row stats (mu, rs) reduced from attn's per-head partials in the prologue.
// ---------------------------------------------------------------------------
__global__ __launch_bounds__(512, 1) void gemm_out8(
    const u16* __restrict__ A, const u16* __restrict__ W,
    const float2* __restrict__ rowpart, const float* __restrict__ S1,
    const float* __restrict__ SB, float* __restrict__ C)
{
    __shared__ __align__(16) u16 lds[49152];   // 96 KiB
    __shared__ float2 rtmp[512];
    __shared__ float2 rowst[128];
    char* ldsb = (char*)lds;

    const int tid = threadIdx.x;
    const int l = tid & 63, w = tid >> 6;
    const int fr = l & 15, fq = l >> 4;

    const int bid = (int)blockIdx.x;
    const int lbid = (bid & 7) * 32 + (bid >> 3);
    const int rt = lbid >> 2, ct = lbid & 3;
    const int brow = rt * 128, bcol = ct * 256;

    // ---- LN row stats: reduce 16 per-head partials per row ----
    {
        int lrow = tid >> 2, grp = tid & 3;
        const float2* rp = rowpart + (size_t)(brow + lrow) * 16 + grp * 4;
        float sx = 0.f, sq = 0.f;
        #pragma unroll
        for (int j = 0; j < 4; j++) { float2 p = rp[j]; sx += p.x; sq += p.y; }
        rtmp[tid] = make_float2(sx, sq);
    }
    __syncthreads();
    if (tid < 128) {
        float sx = 0.f, sq = 0.f;
        #pragma unroll
        for (int j = 0; j < 4; j++) { float2 p = rtmp[tid * 4 + j]; sx += p.x; sq += p.y; }
        float mu = sx * (1.0f / 1024.0f);
        float var = sq * (1.0f / 1024.0f) - mu * mu;
        rowst[tid] = make_float2(mu, rsqrtf(var + 1e-5f));
    }
    __syncthreads();

    const int wr = (w >> 2) * 64, wc = (w & 3) * 64;
    const int hb = (w & 3) >> 1;
    const int rbB = wc & 64;

    const int srow = l >> 3;
    const int sslot = (l & 7) ^ srow;

    const u16* srcA[2];
    const u16* srcB[2][2];
    #pragma unroll
    for (int i = 0; i < 2; i++) {
        int grow = (2 * w + i) * 8 + srow;
        srcA[i] = A + (size_t)(brow + grow) * 1024 + sslot * 8;
    }
    #pragma unroll
    for (int h = 0; h < 2; h++)
        #pragma unroll
        for (int i = 0; i < 2; i++) {
            int grow = h * 128 + (2 * w + i) * 8 + srow;
            srcB[h][i] = W + (size_t)(bcol + grow) * 1024 + sslot * 8;
        }

    auto stageA = [&](int kt, int d) {
        #pragma unroll
        for (int i = 0; i < 2; i++)
            gload_lds16(srcA[i] + kt * 64, ldsb + d * 16384 + (2 * w + i) * 1024);
    };
    auto stageB = [&](int kt, int d) {
        #pragma unroll
        for (int h = 0; h < 2; h++)
            #pragma unroll
            for (int i = 0; i < 2; i++)
                gload_lds16(srcB[h][i] + kt * 64,
                            ldsb + 32768 + d * 32768 + h * 16384 + (2 * w + i) * 1024);
    };

    f32x4 acc[4][4] = {};

    stageA(0, 0); stageB(0, 0);
    asm volatile("s_waitcnt vmcnt(0)" ::: "memory");
    barrier_raw();

    for (int kt = 0; kt < 16; ++kt) {
        const int d = kt & 1, nd = d ^ 1;
        const bool pre = (kt < 15);

        if (pre) stageA(kt + 1, nd);
        #pragma unroll
        for (int kk = 0; kk < 2; kk++) {
            const int sw = ((kk * 4 + fq) ^ (fr & 7)) * 16;
            bf16x8 aF[4], bF[4];
            #pragma unroll
            for (int j = 0; j < 4; j++)
                aF[j] = *reinterpret_cast<const bf16x8*>(
                    ldsb + d * 16384 + ((wr + j * 16 + fr) & 127) * 128 + sw);
            #pragma unroll
            for (int ni = 0; ni < 4; ni++)
                bF[ni] = *reinterpret_cast<const bf16x8*>(
                    ldsb + 32768 + d * 32768 + hb * 16384
                    + (rbB + ni * 16 + fr) * 128 + sw);
            __builtin_amdgcn_s_setprio(1);
            #pragma unroll
            for (int j = 0; j < 4; j++)
                #pragma unroll
                for (int ni = 0; ni < 4; ni++)
                    acc[j][ni] = __builtin_amdgcn_mfma_f32_16x16x32_bf16(
                        aF[j], bF[ni], acc[j][ni], 0, 0, 0);
            __builtin_amdgcn_s_setprio(0);
            if (kk == 0) {
                barrier_raw();
                if (pre) stageB(kt + 1, nd);
            }
        }
        asm volatile("s_waitcnt vmcnt(0)" ::: "memory");
        barrier_raw();
    }

    #pragma unroll
    for (int mi = 0; mi < 4; mi++) {
        int lr0 = wr + mi * 16 + fq * 4;
        int row = brow + lr0;
        #pragma unroll
        for (int ni = 0; ni < 4; ni++) {
            int col = bcol + wc + ni * 16 + fr;
            float s1c = S1[col];
            float sbc = SB[col];
            #pragma unroll
            for (int r = 0; r < 4; r++) {
                float2 st = rowst[lr0 + r];
                C[(size_t)(row + r) * 1024 + col] =
                    st.y * (acc[mi][ni][r] - st.x * s1c) + sbc;
            }
        }
    }
}

// ---------------------------------------------------------------------------
// Flash attention (R16 champion: paired XCD-aware grid, 256 threads,
// double-buffered staging, fixed-shift softmax, matrix-pipe denominator).
// NEW: epilogue also emits per-(row, head) LN partials (sum, sumsq) over
// this head's 64 dims into rowpart[row*16 + h] for the fused-LN out GEMM.
// ---------------------------------------------------------------------------
__global__ __launch_bounds__(256) void attn_kernel(
    const u16* __restrict__ Q, const u16* __restrict__ K,
    const u16* __restrict__ V, u16* __restrict__ O, float2* __restrict__ rowpart)
{
    __shared__ __align__(16) u16 smem[25600];          // 51200 B
    u16* Ks = smem;                                    // [2][64*64]
    u16* Vt = smem + 8192;                             // [2][64*64]
    u16* Ps = smem + 16384;                            // 4 waves * 32 * 72
    float* Ow = (float*)smem;                          // epilogue overlay

    const int tid = threadIdx.x;
    const int l = tid & 63, w = tid >> 6;
    const int fr = l & 15, fq = l >> 4;

    // XCD-aware decode: same-bh blocks share id%8 -> same XCD L2
    const int id = (int)blockIdx.x;
    const int bh = (id & 7) | ((id >> 6) << 3);
    const int px = (id >> 3) & 7;
    const int b = bh >> 4, h = bh & 15;

    const int kp = tid & 31, d0 = (tid >> 5) * 8;
    const int kr = l >> 3, ksw = l & 7;
    u16* Pw = Ps + w * (32 * 72);

    const u16* Kbh = K + (size_t)b * 1024 * 1024 + h * 64;
    const u16* Vbh = V + (size_t)b * 1024 * 1024 + h * 64;

    bf16x8 ones;
    #pragma unroll
    for (int i = 0; i < 8; i++) ones[i] = (__bf16)1.0f;

    for (int half = 0; half < 2; ++half) {
        const int bq = half ? px : 15 - px;
        const int q0 = bq * 128;

        if (half) __syncthreads();

        bf16x8 qf[2][2];
        #pragma unroll
        for (int n = 0; n < 2; n++) {
            size_t qoff = (size_t)(b * 2048 + q0 + w * 32 + n * 16 + fr) * 1024 + h * 64;
            qf[n][0] = *reinterpret_cast<const bf16x8*>(Q + qoff + fq * 8);
            qf[n][1] = *reinterpret_cast<const bf16x8*>(Q + qoff + 32 + fq * 8);
        }

        f32x4 sumac[2] = {};
        f32x4 of[4][2] = {};

        {
            #pragma unroll
            for (int i = 0; i < 2; i++) {
                int cI = w * 2 + i;
                int r = cI * 8 + kr;
                gload_lds16(Kbh + (size_t)r * 1024 + ((ksw ^ (r & 7)) * 8), &Ks[cI * 512]);
            }
            const u16* vp = Vbh + (size_t)(2 * kp) * 1024 + d0;
            uint4 ra = *reinterpret_cast<const uint4*>(vp);
            uint4 rb = *reinterpret_cast<const uint4*>(vp + 1024);
            u16 ea[8], eb[8];
            __builtin_memcpy(ea, &ra, 16);
            __builtin_memcpy(eb, &rb, 16);
            #pragma unroll
            for (int jd = 0; jd < 8; jd++) {
                int d = d0 + jd;
                u32 pk = (u32)ea[jd] | ((u32)eb[jd] << 16);
                *(u32*)((char*)Vt + d * 128 + (((kp >> 2) ^ (d & 7)) * 16) + (kp & 3) * 4) = pk;
            }
        }
        __syncthreads();

        int cur = 0;
        for (int t = 0; t <= bq; ++t) {
            const bool pre = (t < bq);
            uint4 ra, rb;
            if (pre) {
                const int j0n = (t + 1) * 64;
                #pragma unroll
                for (int i = 0; i < 2; i++) {
                    int cI = w * 2 + i;
                    int r = cI * 8 + kr;
                    gload_lds16(Kbh + (size_t)(j0n + r) * 1024 + ((ksw ^ (r & 7)) * 8),
                                &Ks[(cur ^ 1) * 4096 + cI * 512]);
                }
                const u16* vp = Vbh + (size_t)(j0n + 2 * kp) * 1024 + d0;
                ra = *reinterpret_cast<const uint4*>(vp);
                rb = *reinterpret_cast<const uint4*>(vp + 1024);
            }

            // ---- S^T = K * Q^T ----
            f32x4 sf[4][2] = {};
            #pragma unroll
            for (int kk = 0; kk < 2; kk++) {
                bf16x8 kf[4];
                #pragma unroll
                for (int m = 0; m < 4; m++) {
                    int key = m * 16 + fr;
                    kf[m] = *reinterpret_cast<const bf16x8*>(
                        (char*)Ks + cur * 8192 + key * 128 + (((kk * 4 + fq) ^ (key & 7)) * 16));
                }
                #pragma unroll
                for (int m = 0; m < 4; m++)
                    #pragma unroll
                    for (int n = 0; n < 2; n++)
                        sf[m][n] = __builtin_amdgcn_mfma_f32_16x16x32_bf16(
                            kf[m], qf[n][kk], sf[m][n], 0, 0, 0);
            }

            // ---- fixed-shift softmax: P = exp2(s) (masked -> 0) ----
            const bool diag = (t == bq);
            #pragma unroll
            for (int m = 0; m < 4; m++)
                #pragma unroll
                for (int n = 0; n < 2; n++)
                    #pragma unroll
                    for (int r = 0; r < 4; r++) {
                        float s = sf[m][n][r];
                        if (diag) {
                            int kl = m * 16 + fq * 4 + r;
                            int ql = w * 32 + n * 16 + fr;
                            if (kl > (ql >> 1)) s = -1e30f;
                        }
                        sf[m][n][r] = __builtin_amdgcn_exp2f(s);
                    }

            // ---- P -> per-wave LDS ----
            #pragma unroll
            for (int m = 0; m < 4; m++)
                #pragma unroll
                for (int n = 0; n < 2; n++) {
                    bf16x4 pk;
                    pk[0] = (__bf16)sf[m][n][0]; pk[1] = (__bf16)sf[m][n][1];
                    pk[2] = (__bf16)sf[m][n][2]; pk[3] = (__bf16)sf[m][n][3];
                    int q = n * 16 + fr;
                    *(bf16x4*)((char*)Pw + q * 144 + m * 32 + fq * 8) = pk;
                }

            // ---- O^T += V^T * P ; denominator via ones-MFMA ----
            #pragma unroll
            for (int kk = 0; kk < 2; kk++) {
                bf16x8 pf[2], vf[4];
                #pragma unroll
                for (int n = 0; n < 2; n++) {
                    int q = n * 16 + fr;
                    pf[n] = *reinterpret_cast<const bf16x8*>(
                        (char*)Pw + q * 144 + kk * 64 + fq * 16);
                }
                #pragma unroll
                for (int m = 0; m < 4; m++) {
                    int d = m * 16 + fr;
                    vf[m] = *reinterpret_cast<const bf16x8*>(
                        (char*)Vt + cur * 8192 + d * 128 + (((kk * 4 + fq) ^ (d & 7)) * 16));
                }
                #pragma unroll
                for (int m = 0; m < 4; m++)
                    #pragma unroll
                    for (int n = 0; n < 2; n++)
                        of[m][n] = __builtin_amdgcn_mfma_f32_16x16x32_bf16(
                            vf[m], pf[n], of[m][n], 0, 0, 0);
                #pragma unroll
                for (int n = 0; n < 2; n++)
                    sumac[n] = __builtin_amdgcn_mfma_f32_16x16x32_bf16(
                        ones, pf[n], sumac[n], 0, 0, 0);
            }

            if (pre) {
                u16 ea[8], eb[8];
                __builtin_memcpy(ea, &ra, 16);
                __builtin_memcpy(eb, &rb, 16);
                #pragma unroll
                for (int jd = 0; jd < 8; jd++) {
                    int d = d0 + jd;
                    u32 pk = (u32)ea[jd] | ((u32)eb[jd] << 16);
                    *(u32*)((char*)Vt + (cur ^ 1) * 8192 + d * 128
                            + (((kp >> 2) ^ (d & 7)) * 16) + (kp & 3) * 4) = pk;
                }
            }
            __syncthreads();
            cur ^= 1;
        }

        // ---- epilogue: normalize + LN partials, transpose, store ----
        float* OwW = Ow + w * (32 * 68);
        float psum[2] = {0.f, 0.f}, psq[2] = {0.f, 0.f};
        #pragma unroll
        for (int n = 0; n < 2; n++) {
            float inv = 1.0f / sumac[n][0];
            #pragma unroll
            for (int m = 0; m < 4; m++) {
                f32x4 v = of[m][n] * inv;
                int q = n * 16 + fr;
                *reinterpret_cast<f32x4*>(&OwW[q * 68 + m * 16 + fq * 4]) = v;
                psum[n] += v[0] + v[1] + v[2] + v[3];
                psq[n]  += v[0]*v[0] + v[1]*v[1] + v[2]*v[2] + v[3]*v[3];
            }
        }
        #pragma unroll
        for (int n = 0; n < 2; n++) {
            psum[n] += __shfl_xor(psum[n], 16);
            psum[n] += __shfl_xor(psum[n], 32);
            psq[n]  += __shfl_xor(psq[n], 16);
            psq[n]  += __shfl_xor(psq[n], 32);
        }
        if (fq == 0) {
            #pragma unroll
            for (int n = 0; n < 2; n++) {
                size_t grow = (size_t)(b * 2048 + q0 + w * 32 + n * 16 + fr);
                rowpart[grow * 16 + h] = make_float2(psum[n], psq[n]);
            }
        }
        {
            int ql = l >> 1, dh = l & 1;
            size_t grow = (size_t)(b * 2048 + q0 + w * 32 + ql) * 1024 + h * 64 + dh * 32;
            #pragma unroll
            for (int p = 0; p < 4; p++) {
                f32x4 a = *reinterpret_cast<const f32x4*>(&OwW[ql * 68 + dh * 32 + p * 8]);
                f32x4 c = *reinterpret_cast<const f32x4*>(&OwW[ql * 68 + dh * 32 + p * 8 + 4]);
                bf16x8 pk;
                pk[0]=(__bf16)a[0]; pk[1]=(__bf16)a[1]; pk[2]=(__bf16)a[2]; pk[3]=(__bf16)a[3];
                pk[4]=(__bf16)c[0]; pk[5]=(__bf16)c[1]; pk[6]=(__bf16)c[2]; pk[7]=(__bf16)c[3];
                *reinterpret_cast<bf16x8*>(O + grow + p * 8) = pk;
            }
        }
    }
}

// ---------------------------------------------------------------------------
extern "C" void kernel_launch(void* const* d_in, const int* in_sizes, int n_in,
                              void* d_out, int out_size, void* d_ws, size_t ws_size,
                              hipStream_t stream)
{
    const float* q    = (const float*)d_in[0];
    const float* kv   = (const float*)d_in[1];
    const float* Wq   = (const float*)d_in[2];
    const float* Wk   = (const float*)d_in[3];
    const float* Wv   = (const float*)d_in[4];
    const float* Wo   = (const float*)d_in[5];
    const float* bo   = (const float*)d_in[6];
    const float* ln_g = (const float*)d_in[7];
    const float* ln_b = (const float*)d_in[8];

    const size_t MQ = (size_t)8192 * 1024;
    const size_t MK = (size_t)4096 * 1024;
    const size_t MW = (size_t)1024 * 1024;

    u16* q8  = (u16*)d_ws;           // contiguous: q8,kv8,Wq8,Wk8,Wv8,Wo8
    u16* kv8 = q8 + MQ;
    u16* Wq8 = kv8 + MK;
    u16* Wk8 = Wq8 + MW;
    u16* Wv8 = Wk8 + MW;
    u16* Wo8 = Wv8 + MW;
    u16* Qb  = Wo8 + MW;
    u16* Kb  = Qb + MQ;
    u16* Vb  = Kb + MK;
    u16* Ab  = Vb + MK;
    float* S1 = (float*)(Ab + MQ);   // 1024 f32
    float* SB = S1 + 1024;           // 1024 f32
    float2* rowpart = (float2*)q8;   // overlay: q8 dead after gemm_qkv8 (1 MB)

    cvt_all<<<2304, 256, 0, stream>>>(q, kv, Wq, Wk, Wv, Wo, ln_g, ln_b, bo,
                                      q8, S1, SB);
    gemm_qkv8<<<256, 512, 0, stream>>>(q8, kv8, Wq8, Wk8, Wv8, Qb, Kb, Vb);
    attn_kernel<<<512, 256, 0, stream>>>(Qb, Kb, Vb, Ab, rowpart);
    gemm_out8<<<256, 512, 0, stream>>>(Ab, Wo8, rowpart, S1, SB, (float*)d_out);
}

// Round 18
// 121.006 us; speedup vs baseline: 1.0156x; 1.0156x over previous
//
#include <hip/hip_runtime.h>

typedef unsigned short u16;
typedef unsigned int   u32;

typedef __bf16 bf16x8 __attribute__((ext_vector_type(8)));
typedef __bf16 bf16x4 __attribute__((ext_vector_type(4)));
typedef float  f32x4  __attribute__((ext_vector_type(4)));

__device__ __forceinline__ float bf2f(u16 v) {
    u32 u = ((u32)v) << 16; float f; __builtin_memcpy(&f, &u, 4); return f;
}
__device__ __forceinline__ u16 f2bf(float f) {
    __bf16 h = (__bf16)f; u16 r; __builtin_memcpy(&r, &h, 2); return r;
}

__device__ __forceinline__ void gload_lds16(const void* g, void* l) {
    __builtin_amdgcn_global_load_lds(
        (const __attribute__((address_space(1))) u32*)g,
        (__attribute__((address_space(3))) u32*)l, 16, 0, 0);
}

__device__ __forceinline__ void barrier_raw() {
    __builtin_amdgcn_s_barrier();
    asm volatile("" ::: "memory");
}

// Q-projection scale: 1/sqrt(64) * log2(e)  (base-2 softmax)
#define QSCALE 0.1803368801111204f

// ---------------------------------------------------------------------------
// Fused f32 -> bf16 conversion of all 6 tensors (contiguous ws dest).
// ---------------------------------------------------------------------------
__global__ __launch_bounds__(256) void cvt_all(
    const float* __restrict__ q, const float* __restrict__ kv,
    const float* __restrict__ Wq, const float* __restrict__ Wk,
    const float* __restrict__ Wv, const float* __restrict__ Wo,
    u16* __restrict__ dst)
{
    const int total = 16 << 18;
    int i = blockIdx.x * 256 + threadIdx.x;
    const int stride = gridDim.x * 256;
    for (; i < total; i += stride) {
        int seg = i >> 18;
        const float* s; int off;
        if (seg < 8)        { s = q;  off = i; }
        else if (seg < 12)  { s = kv; off = i - (8 << 18); }
        else if (seg == 12) { s = Wq; off = i & 262143; }
        else if (seg == 13) { s = Wk; off = i & 262143; }
        else if (seg == 14) { s = Wv; off = i & 262143; }
        else                { s = Wo; off = i & 262143; }
        float4 v = reinterpret_cast<const float4*>(s)[off];
        ushort4 o;
        o.x = f2bf(v.x); o.y = f2bf(v.y); o.z = f2bf(v.z); o.w = f2bf(v.w);
        reinterpret_cast<ushort4*>(dst)[i] = o;
    }
}

// ---------------------------------------------------------------------------
// 256x256 8-wave phased GEMM for the QKV projections (validated R7).
// ---------------------------------------------------------------------------
template<int KK, int MH, bool RB>
__device__ __forceinline__ void qkv_phase(
    const char* ldsb, int d, int ha, int hb, int rbB, int fr, int fq,
    bf16x8 (&bF)[4], f32x4 (&acc)[8][4])
{
    const int sw = ((KK * 4 + fq) ^ (fr & 7)) * 16;
    if (RB) {
        #pragma unroll
        for (int ni = 0; ni < 4; ni++)
            bF[ni] = *reinterpret_cast<const bf16x8*>(
                ldsb + 65536 + d * 32768 + hb * 16384 + (rbB + ni * 16 + fr) * 128 + sw);
    }
    bf16x8 aF[4];
    #pragma unroll
    for (int j = 0; j < 4; j++)
        aF[j] = *reinterpret_cast<const bf16x8*>(
            ldsb + d * 32768 + ha * 16384 + ((MH * 4 + j) * 16 + fr) * 128 + sw);
    __builtin_amdgcn_s_setprio(1);
    #pragma unroll
    for (int j = 0; j < 4; j++)
        #pragma unroll
        for (int ni = 0; ni < 4; ni++)
            acc[MH * 4 + j][ni] = __builtin_amdgcn_mfma_f32_16x16x32_bf16(
                aF[j], bF[ni], acc[MH * 4 + j][ni], 0, 0, 0);
    __builtin_amdgcn_s_setprio(0);
}

__global__ __launch_bounds__(512, 2) void gemm_qkv8(
    const u16* __restrict__ q8, const u16* __restrict__ kv8,
    const u16* __restrict__ Wq8, const u16* __restrict__ Wk8,
    const u16* __restrict__ Wv8,
    u16* __restrict__ Qb, u16* __restrict__ Kb, u16* __restrict__ Vb)
{
    __shared__ __align__(16) u16 lds[65536];   // 128 KiB
    char* ldsb = (char*)lds;

    const int tid = threadIdx.x;
    const int l = tid & 63, w = tid >> 6;
    const int fr = l & 15, fq = l >> 4;

    const int bid = (int)blockIdx.x;
    const int lbid = (bid & 7) * 32 + (bid >> 3);
    const u16 *A, *W; u16* C; float scale = 1.0f; int rt, ct;
    if (lbid < 128)      { A = q8;  W = Wq8; C = Qb; scale = QSCALE; rt = lbid >> 2; ct = lbid & 3; }
    else if (lbid < 192) { int t = lbid - 128; A = kv8; W = Wk8; C = Kb; rt = t >> 2; ct = t & 3; }
    else                 { int t = lbid - 192; A = kv8; W = Wv8; C = Vb; rt = t >> 2; ct = t & 3; }
    const int brow = rt * 256, bcol = ct * 256;

    const int wr = (w >> 2) * 128, wc = (w & 3) * 64;
    const int ha = w >> 2;
    const int hb = (w & 3) >> 1;
    const int rbB = wc & 64;

    const int srow = l >> 3;
    const int sslot = (l & 7) ^ srow;

    const u16* srcA[2][2];
    const u16* srcB[2][2];
    #pragma unroll
    for (int h = 0; h < 2; h++)
        #pragma unroll
        for (int i = 0; i < 2; i++) {
            int grow = h * 128 + (2 * w + i) * 8 + srow;
            srcA[h][i] = A + (size_t)(brow + grow) * 1024 + sslot * 8;
            srcB[h][i] = W + (size_t)(bcol + grow) * 1024 + sslot * 8;
        }

    auto stageA = [&](int kt, int d) {
        #pragma unroll
        for (int h = 0; h < 2; h++)
            #pragma unroll
            for (int i = 0; i < 2; i++)
                gload_lds16(srcA[h][i] + kt * 64,
                            ldsb + d * 32768 + h * 16384 + (2 * w + i) * 1024);
    };
    auto stageBh = [&](int kt, int d, int h) {
        #pragma unroll
        for (int i = 0; i < 2; i++)
            gload_lds16(srcB[h][i] + kt * 64,
                        ldsb + 65536 + d * 32768 + h * 16384 + (2 * w + i) * 1024);
    };

    f32x4 acc[8][4] = {};

    stageA(0, 0); stageBh(0, 0, 0); stageBh(0, 0, 1);
    asm volatile("s_waitcnt vmcnt(0)" ::: "memory");
    barrier_raw();

    for (int kt = 0; kt < 16; ++kt) {
        const int d = kt & 1, nd = d ^ 1;
        const bool pre = (kt < 15);
        bf16x8 bF[4];

        if (pre) stageA(kt + 1, nd);
        qkv_phase<0, 0, true >(ldsb, d, ha, hb, rbB, fr, fq, bF, acc);
        barrier_raw();
        if (pre) stageBh(kt + 1, nd, 0);
        qkv_phase<0, 1, false>(ldsb, d, ha, hb, rbB, fr, fq, bF, acc);
        barrier_raw();
        if (pre) stageBh(kt + 1, nd, 1);
        qkv_phase<1, 0, true >(ldsb, d, ha, hb, rbB, fr, fq, bF, acc);
        barrier_raw();
        qkv_phase<1, 1, false>(ldsb, d, ha, hb, rbB, fr, fq, bF, acc);
        asm volatile("s_waitcnt vmcnt(0)" ::: "memory");
        barrier_raw();
    }

    #pragma unroll
    for (int mi = 0; mi < 8; mi++) {
        int row = brow + wr + mi * 16 + fq * 4;
        #pragma unroll
        for (int ni = 0; ni < 4; ni++) {
            int col = bcol + wc + ni * 16 + fr;
            #pragma unroll
            for (int r = 0; r < 4; r++)
                C[(size_t)(row + r) * 1024 + col] = f2bf(acc[mi][ni][r] * scale);
        }
    }
}

// ---------------------------------------------------------------------------
// 128x256 8-wave phased GEMM for the output projection (validated R8).
// ---------------------------------------------------------------------------
__global__ __launch_bounds__(512, 1) void gemm_out8(
    const u16* __restrict__ A, const u16* __restrict__ W,
    const float* __restrict__ bias, float* __restrict__ C)
{
    __shared__ __align__(16) u16 lds[49152];   // 96 KiB
    char* ldsb = (char*)lds;

    const int tid = threadIdx.x;
    const int l = tid & 63, w = tid >> 6;
    const int fr = l & 15, fq = l >> 4;

    const int bid = (int)blockIdx.x;
    const int lbid = (bid & 7) * 32 + (bid >> 3);
    const int rt = lbid >> 2, ct = lbid & 3;
    const int brow = rt * 128, bcol = ct * 256;

    const int wr = (w >> 2) * 64, wc = (w & 3) * 64;
    const int hb = (w & 3) >> 1;
    const int rbB = wc & 64;

    const int srow = l >> 3;
    const int sslot = (l & 7) ^ srow;

    const u16* srcA[2];
    const u16* srcB[2][2];
    #pragma unroll
    for (int i = 0; i < 2; i++) {
        int grow = (2 * w + i) * 8 + srow;
        srcA[i] = A + (size_t)(brow + grow) * 1024 + sslot * 8;
    }
    #pragma unroll
    for (int h = 0; h < 2; h++)
        #pragma unroll
        for (int i = 0; i < 2; i++) {
            int grow = h * 128 + (2 * w + i) * 8 + srow;
            srcB[h][i] = W + (size_t)(bcol + grow) * 1024 + sslot * 8;
        }

    auto stageA = [&](int kt, int d) {
        #pragma unroll
        for (int i = 0; i < 2; i++)
            gload_lds16(srcA[i] + kt * 64, ldsb + d * 16384 + (2 * w + i) * 1024);
    };
    auto stageB = [&](int kt, int d) {
        #pragma unroll
        for (int h = 0; h < 2; h++)
            #pragma unroll
            for (int i = 0; i < 2; i++)
                gload_lds16(srcB[h][i] + kt * 64,
                            ldsb + 32768 + d * 32768 + h * 16384 + (2 * w + i) * 1024);
    };

    f32x4 acc[4][4] = {};

    stageA(0, 0); stageB(0, 0);
    asm volatile("s_waitcnt vmcnt(0)" ::: "memory");
    barrier_raw();

    for (int kt = 0; kt < 16; ++kt) {
        const int d = kt & 1, nd = d ^ 1;
        const bool pre = (kt < 15);

        if (pre) stageA(kt + 1, nd);
        #pragma unroll
        for (int kk = 0; kk < 2; kk++) {
            const int sw = ((kk * 4 + fq) ^ (fr & 7)) * 16;
            bf16x8 aF[4], bF[4];
            #pragma unroll
            for (int j = 0; j < 4; j++)
                aF[j] = *reinterpret_cast<const bf16x8*>(
                    ldsb + d * 16384 + ((wr + j * 16 + fr) & 127) * 128 + sw);
            #pragma unroll
            for (int ni = 0; ni < 4; ni++)
                bF[ni] = *reinterpret_cast<const bf16x8*>(
                    ldsb + 32768 + d * 32768 + hb * 16384
                    + (rbB + ni * 16 + fr) * 128 + sw);
            __builtin_amdgcn_s_setprio(1);
            #pragma unroll
            for (int j = 0; j < 4; j++)
                #pragma unroll
                for (int ni = 0; ni < 4; ni++)
                    acc[j][ni] = __builtin_amdgcn_mfma_f32_16x16x32_bf16(
                        aF[j], bF[ni], acc[j][ni], 0, 0, 0);
            __builtin_amdgcn_s_setprio(0);
            if (kk == 0) {
                barrier_raw();
                if (pre) stageB(kt + 1, nd);
            }
        }
        asm volatile("s_waitcnt vmcnt(0)" ::: "memory");
        barrier_raw();
    }

    #pragma unroll
    for (int mi = 0; mi < 4; mi++) {
        int row = brow + wr + mi * 16 + fq * 4;
        #pragma unroll
        for (int ni = 0; ni < 4; ni++) {
            int col = bcol + wc + ni * 16 + fr;
            float bv = bias[col];
            #pragma unroll
            for (int r = 0; r < 4; r++)
                C[(size_t)(row + r) * 1024 + col] = acc[mi][ni][r] + bv;
        }
    }
}

// ---------------------------------------------------------------------------
// Flash attention: R16 champion. Paired XCD-aware grid (512 blocks,
// id = (bh&7) | (pair<<3) | ((bh>>3)<<6) so same-bh blocks share an XCD L2),
// 256 threads, double-buffered K/V staging via global_load_lds with
// source-swizzled involution, fixed-shift base-2 softmax (no max tracking),
// softmax denominator accumulated on the matrix pipe (ones-MFMA).
// ---------------------------------------------------------------------------
__global__ __launch_bounds__(256) void attn_kernel(
    const u16* __restrict__ Q, const u16* __restrict__ K,
    const u16* __restrict__ V, u16* __restrict__ O)
{
    __shared__ __align__(16) u16 smem[25600];          // 51200 B
    u16* Ks = smem;                                    // [2][64*64]
    u16* Vt = smem + 8192;                             // [2][64*64]
    u16* Ps = smem + 16384;                            // 4 waves * 32 * 72
    float* Ow = (float*)smem;                          // epilogue overlay

    const int tid = threadIdx.x;
    const int l = tid & 63, w = tid >> 6;
    const int fr = l & 15, fq = l >> 4;

    const int id = (int)blockIdx.x;
    const int bh = (id & 7) | ((id >> 6) << 3);
    const int px = (id >> 3) & 7;
    const int b = bh >> 4, h = bh & 15;

    const int kp = tid & 31, d0 = (tid >> 5) * 8;
    const int kr = l >> 3, ksw = l & 7;
    u16* Pw = Ps + w * (32 * 72);

    const u16* Kbh = K + (size_t)b * 1024 * 1024 + h * 64;
    const u16* Vbh = V + (size_t)b * 1024 * 1024 + h * 64;

    bf16x8 ones;
    #pragma unroll
    for (int i = 0; i < 8; i++) ones[i] = (__bf16)1.0f;

    for (int half = 0; half < 2; ++half) {
        const int bq = half ? px : 15 - px;
        const int q0 = bq * 128;

        if (half) __syncthreads();

        bf16x8 qf[2][2];
        #pragma unroll
        for (int n = 0; n < 2; n++) {
            size_t qoff = (size_t)(b * 2048 + q0 + w * 32 + n * 16 + fr) * 1024 + h * 64;
            qf[n][0] = *reinterpret_cast<const bf16x8*>(Q + qoff + fq * 8);
            qf[n][1] = *reinterpret_cast<const bf16x8*>(Q + qoff + 32 + fq * 8);
        }

        f32x4 sumac[2] = {};
        f32x4 of[4][2] = {};

        {
            #pragma unroll
            for (int i = 0; i < 2; i++) {
                int cI = w * 2 + i;
                int r = cI * 8 + kr;
                gload_lds16(Kbh + (size_t)r * 1024 + ((ksw ^ (r & 7)) * 8), &Ks[cI * 512]);
            }
            const u16* vp = Vbh + (size_t)(2 * kp) * 1024 + d0;
            uint4 ra = *reinterpret_cast<const uint4*>(vp);
            uint4 rb = *reinterpret_cast<const uint4*>(vp + 1024);
            u16 ea[8], eb[8];
            __builtin_memcpy(ea, &ra, 16);
            __builtin_memcpy(eb, &rb, 16);
            #pragma unroll
            for (int jd = 0; jd < 8; jd++) {
                int d = d0 + jd;
                u32 pk = (u32)ea[jd] | ((u32)eb[jd] << 16);
                *(u32*)((char*)Vt + d * 128 + (((kp >> 2) ^ (d & 7)) * 16) + (kp & 3) * 4) = pk;
            }
        }
        __syncthreads();

        int cur = 0;
        for (int t = 0; t <= bq; ++t) {
            const bool pre = (t < bq);
            uint4 ra, rb;
            if (pre) {
                const int j0n = (t + 1) * 64;
                #pragma unroll
                for (int i = 0; i < 2; i++) {
                    int cI = w * 2 + i;
                    int r = cI * 8 + kr;
                    gload_lds16(Kbh + (size_t)(j0n + r) * 1024 + ((ksw ^ (r & 7)) * 8),
                                &Ks[(cur ^ 1) * 4096 + cI * 512]);
                }
                const u16* vp = Vbh + (size_t)(j0n + 2 * kp) * 1024 + d0;
                ra = *reinterpret_cast<const uint4*>(vp);
                rb = *reinterpret_cast<const uint4*>(vp + 1024);
            }

            // ---- S^T = K * Q^T ----
            f32x4 sf[4][2] = {};
            #pragma unroll
            for (int kk = 0; kk < 2; kk++) {
                bf16x8 kf[4];
                #pragma unroll
                for (int m = 0; m < 4; m++) {
                    int key = m * 16 + fr;
                    kf[m] = *reinterpret_cast<const bf16x8*>(
                        (char*)Ks + cur * 8192 + key * 128 + (((kk * 4 + fq) ^ (key & 7)) * 16));
                }
                #pragma unroll
                for (int m = 0; m < 4; m++)
                    #pragma unroll
                    for (int n = 0; n < 2; n++)
                        sf[m][n] = __builtin_amdgcn_mfma_f32_16x16x32_bf16(
                            kf[m], qf[n][kk], sf[m][n], 0, 0, 0);
            }

            // ---- fixed-shift softmax: P = exp2(s) (masked -> 0) ----
            const bool diag = (t == bq);
            #pragma unroll
            for (int m = 0; m < 4; m++)
                #pragma unroll
                for (int n = 0; n < 2; n++)
                    #pragma unroll
                    for (int r = 0; r < 4; r++) {
                        float s = sf[m][n][r];
                        if (diag) {
                            int kl = m * 16 + fq * 4 + r;
                            int ql = w * 32 + n * 16 + fr;
                            if (kl > (ql >> 1)) s = -1e30f;
                        }
                        sf[m][n][r] = __builtin_amdgcn_exp2f(s);
                    }

            // ---- P -> per-wave LDS ----
            #pragma unroll
            for (int m = 0; m < 4; m++)
                #pragma unroll
                for (int n = 0; n < 2; n++) {
                    bf16x4 pk;
                    pk[0] = (__bf16)sf[m][n][0]; pk[1] = (__bf16)sf[m][n][1];
                    pk[2] = (__bf16)sf[m][n][2]; pk[3] = (__bf16)sf[m][n][3];
                    int q = n * 16 + fr;
                    *(bf16x4*)((char*)Pw + q * 144 + m * 32 + fq * 8) = pk;
                }

            // ---- O^T += V^T * P ; denominator via ones-MFMA ----
            #pragma unroll
            for (int kk = 0; kk < 2; kk++) {
                bf16x8 pf[2], vf[4];
                #pragma unroll
                for (int n = 0; n < 2; n++) {
                    int q = n * 16 + fr;
                    pf[n] = *reinterpret_cast<const bf16x8*>(
                        (char*)Pw + q * 144 + kk * 64 + fq * 16);
                }
                #pragma unroll
                for (int m = 0; m < 4; m++) {
                    int d = m * 16 + fr;
                    vf[m] = *reinterpret_cast<const bf16x8*>(
                        (char*)Vt + cur * 8192 + d * 128 + (((kk * 4 + fq) ^ (d & 7)) * 16));
                }
                #pragma unroll
                for (int m = 0; m < 4; m++)
                    #pragma unroll
                    for (int n = 0; n < 2; n++)
                        of[m][n] = __builtin_amdgcn_mfma_f32_16x16x32_bf16(
                            vf[m], pf[n], of[m][n], 0, 0, 0);
                #pragma unroll
                for (int n = 0; n < 2; n++)
                    sumac[n] = __builtin_amdgcn_mfma_f32_16x16x32_bf16(
                        ones, pf[n], sumac[n], 0, 0, 0);
            }

            if (pre) {
                u16 ea[8], eb[8];
                __builtin_memcpy(ea, &ra, 16);
                __builtin_memcpy(eb, &rb, 16);
                #pragma unroll
                for (int jd = 0; jd < 8; jd++) {
                    int d = d0 + jd;
                    u32 pk = (u32)ea[jd] | ((u32)eb[jd] << 16);
                    *(u32*)((char*)Vt + (cur ^ 1) * 8192 + d * 128
                            + (((kp >> 2) ^ (d & 7)) * 16) + (kp & 3) * 4) = pk;
                }
            }
            __syncthreads();
            cur ^= 1;
        }

        float* OwW = Ow + w * (32 * 68);
        #pragma unroll
        for (int m = 0; m < 4; m++)
            #pragma unroll
            for (int n = 0; n < 2; n++) {
                f32x4 v = of[m][n] * (1.0f / sumac[n][0]);
                int q = n * 16 + fr;
                *reinterpret_cast<f32x4*>(&OwW[q * 68 + m * 16 + fq * 4]) = v;
            }
        {
            int ql = l >> 1, dh = l & 1;
            size_t grow = (size_t)(b * 2048 + q0 + w * 32 + ql) * 1024 + h * 64 + dh * 32;
            #pragma unroll
            for (int p = 0; p < 4; p++) {
                f32x4 a = *reinterpret_cast<const f32x4*>(&OwW[ql * 68 + dh * 32 + p * 8]);
                f32x4 c = *reinterpret_cast<const f32x4*>(&OwW[ql * 68 + dh * 32 + p * 8 + 4]);
                bf16x8 pk;
                pk[0]=(__bf16)a[0]; pk[1]=(__bf16)a[1]; pk[2]=(__bf16)a[2]; pk[3]=(__bf16)a[3];
                pk[4]=(__bf16)c[0]; pk[5]=(__bf16)c[1]; pk[6]=(__bf16)c[2]; pk[7]=(__bf16)c[3];
                *reinterpret_cast<bf16x8*>(O + grow + p * 8) = pk;
            }
        }
    }
}

// ---------------------------------------------------------------------------
// LayerNorm in-place over rows of [8192][1024], bf16 data, f32 params/accum.
// ---------------------------------------------------------------------------
__global__ __launch_bounds__(256) void ln_kernel(
    u16* __restrict__ buf, const float* __restrict__ g, const float* __restrict__ beta)
{
    const int row = blockIdx.x, tid = threadIdx.x;
    const size_t base = (size_t)row * 1024;
    ushort4 v = *reinterpret_cast<const ushort4*>(&buf[base + tid * 4]);
    float x0 = bf2f(v.x), x1 = bf2f(v.y), x2 = bf2f(v.z), x3 = bf2f(v.w);
    float s = x0 + x1 + x2 + x3;
    float q = x0 * x0 + x1 * x1 + x2 * x2 + x3 * x3;
    #pragma unroll
    for (int d = 32; d; d >>= 1) { s += __shfl_xor(s, d); q += __shfl_xor(q, d); }
    __shared__ float sm[8];
    int w = tid >> 6, l = tid & 63;
    if (l == 0) { sm[w] = s; sm[4 + w] = q; }
    __syncthreads();
    s = sm[0] + sm[1] + sm[2] + sm[3];
    q = sm[4] + sm[5] + sm[6] + sm[7];
    float mean = s * (1.0f / 1024.0f);
    float var = q * (1.0f / 1024.0f) - mean * mean;
    float rstd = rsqrtf(var + 1e-5f);
    float4 gv = *reinterpret_cast<const float4*>(&g[tid * 4]);
    float4 bv = *reinterpret_cast<const float4*>(&beta[tid * 4]);
    ushort4 o;
    o.x = f2bf((x0 - mean) * rstd * gv.x + bv.x);
    o.y = f2bf((x1 - mean) * rstd * gv.y + bv.y);
    o.z = f2bf((x2 - mean) * rstd * gv.z + bv.z);
    o.w = f2bf((x3 - mean) * rstd * gv.w + bv.w);
    *reinterpret_cast<ushort4*>(&buf[base + tid * 4]) = o;
}

// ---------------------------------------------------------------------------
extern "C" void kernel_launch(void* const* d_in, const int* in_sizes, int n_in,
                              void* d_out, int out_size, void* d_ws, size_t ws_size,
                              hipStream_t stream)
{
    const float* q    = (const float*)d_in[0];
    const float* kv   = (const float*)d_in[1];
    const float* Wq   = (const float*)d_in[2];
    const float* Wk   = (const float*)d_in[3];
    const float* Wv   = (const float*)d_in[4];
    const float* Wo   = (const float*)d_in[5];
    const float* bo   = (const float*)d_in[6];
    const float* ln_g = (const float*)d_in[7];
    const float* ln_b = (const float*)d_in[8];

    const size_t MQ = (size_t)8192 * 1024;
    const size_t MK = (size_t)4096 * 1024;
    const size_t MW = (size_t)1024 * 1024;

    u16* q8  = (u16*)d_ws;           // contiguous: q8,kv8,Wq8,Wk8,Wv8,Wo8
    u16* kv8 = q8 + MQ;
    u16* Wq8 = kv8 + MK;
    u16* Wk8 = Wq8 + MW;
    u16* Wv8 = Wk8 + MW;
    u16* Wo8 = Wv8 + MW;
    u16* Qb  = Wo8 + MW;
    u16* Kb  = Qb + MQ;
    u16* Vb  = Kb + MK;
    u16* Ab  = Vb + MK;

    cvt_all<<<2048, 256, 0, stream>>>(q, kv, Wq, Wk, Wv, Wo, q8);
    gemm_qkv8<<<256, 512, 0, stream>>>(q8, kv8, Wq8, Wk8, Wv8, Qb, Kb, Vb);
    attn_kernel<<<512, 256, 0, stream>>>(Qb, Kb, Vb, Ab);
    ln_kernel<<<8192, 256, 0, stream>>>(Ab, ln_g, ln_b);
    gemm_out8<<<256, 512, 0, stream>>>(Ab, Wo8, bo, (float*)d_out);
}